// Round 6
// baseline (161.778 us; speedup 1.0000x reference)
//
#include <hip/hip_runtime.h>

#define B_ 2048
#define T_ 500
#define N_ 64
#define BT (B_ * T_)

// ---------------------------------------------------------------------------
// Kernel 1: row sums.  S[r] = sum_n input[r*64 + n],  r = b*T + t.
// 16 lanes cooperate per row; fully coalesced 1 KB/wave loads. HBM roofline.
// ---------------------------------------------------------------------------
__global__ __launch_bounds__(256) void rowsum_kernel(const float* __restrict__ in,
                                                     float* __restrict__ S) {
    long long gid = (long long)blockIdx.x * 256 + threadIdx.x;  // chunk index
    const float4* p = (const float4*)in;
    float4 v = p[gid];
    float s = (v.x + v.y) + (v.z + v.w);
    s += __shfl_xor(s, 1);
    s += __shfl_xor(s, 2);
    s += __shfl_xor(s, 4);
    s += __shfl_xor(s, 8);
    if ((threadIdx.x & 15) == 0) S[gid >> 4] = s;
}

// ---------------------------------------------------------------------------
// Izhikevich Euler step — association order matches the reference exactly.
// DT = 0.25; all neuron types have a = 0.02 -> DT*a = 0.005f.
// ---------------------------------------------------------------------------
__device__ __forceinline__ float izh(float& v, float& u, float I,
                                     float b, float c, float d) {
    float t  = 0.04f * v * v + 5.0f * v + 140.0f - u + I;
    float v_ = v + 0.25f * t;
    float u_ = u + 0.005f * (b * v - u);
    float z  = (v_ >= 30.0f) ? 1.0f : 0.0f;
    v = (v_ >= 30.0f) ? c : v_;
    u = u_ + z * d;
    return z;
}

// ---------------------------------------------------------------------------
// Kernel 2: one channel per wave; neurons software-pipelined across time with
// uniform store-time t = j-4:  L(j), E(j-1), I(j-2), T(j-2), M(j-4).
// Outputs staged per 16-step tile in t-major LDS ([t][lane], pad 65 -> both
// write and transpose-read sides are bank-conflict-free/minimal), dumped as
// full-line coalesced wave-stores (the data-minimum 40 line-touches/step,
// vs ~256 scattered before). Block = 64 threads = 1 wave.
// Grid = 64 blocks: [0,32) = channel 1, [32,64) = channel 2.
// ---------------------------------------------------------------------------
__global__ __launch_bounds__(64) void scan_pipe_lds_kernel(const float* __restrict__ S,
                                                           const float* __restrict__ w24,
                                                           float* __restrict__ out) {
    __shared__ float  l0[16][65];   // z6  (o_spikes / o_spikes2)
    __shared__ float  l1[16][65];   // vM  (v / v2)
    __shared__ float4 l4[16][65];   // o_spikes_o (ch1 blocks only)
    __shared__ float4 l5[16][65];   // v_o        (ch1 blocks only)

    const int lane = threadIdx.x;
    const int ch   = (blockIdx.x >= 32) ? 1 : 0;
    const int brow = (blockIdx.x & 31) * 64;
    const int b    = brow + lane;

    const float a0  = ch ? w24[12] : w24[0];
    const float a1  = ch ? w24[13] : w24[1];
    const float w2c = w24[2],  w3c = w24[3];
    const float a4  = ch ? w24[16] : w24[4];
    const float a5  = ch ? w24[17] : w24[5];
    const float a6  = ch ? w24[18] : w24[6];
    const float a8  = ch ? w24[20] : w24[8];
    const float w9c = w24[9],  w10c = w24[10];
    const float a11 = ch ? w24[23] : w24[11];

    float vL = -70.f, uL = -14.f;
    float vE = -64.f, uE = -16.f;
    float vI = -64.f, uI = -16.f;
    float vT = -70.f, uT = -14.f;
    float vM = -64.f, uM = -16.f;
    // histories (value at entry of iteration j):
    float zL = 0.f;      // z2(j-1)
    float zph = 0.f;     // zp(j-1)
    float z2h2 = 0.f;    // z2(j-2)
    float z3h = 0.f;     // z3(j-2)
    float z5h1 = 0.f;    // z5(j-3)
    float z5h2 = 0.f;    // z5(j-4)
    float vLh = -70.f;   // vL(j-2)
    float4 P4_d1 = make_float4(0,0,0,0), P4_d2 = make_float4(0,0,0,0);  // built t=j-2 / t=j-3... stored t=j-4
    float4 P5_d1 = make_float4(0,0,0,0), P5_d2 = make_float4(0,0,0,0);

    const float4* S4 = (const float4*)(S + (size_t)b * T_);
    float* q0base = out + (size_t)(ch ? 2 : 0) * BT;   // + row*T + t
    float* q1base = out + (size_t)(ch ? 3 : 1) * BT;
    float4* p4base = (float4*)out + (size_t)BT;        // o_spikes_o, float4 idx row*T+t
    float4* p5base = (float4*)out + (size_t)2 * BT;    // v_o

#define FULL_ITER(SSUM, K)  {                                                  \
    float zpc = (SSUM) * a0;                                                   \
    float zLs = zL, vLp = vL, vEp = vE;                                        \
    float z2n = izh(vL, uL, w2c * (zpc * a1) + w3c * zLs, 0.20f, -65.f, 6.f);  \
    float z3n = izh(vE, uE, zph * a4 + zLs * a5,          0.25f, -55.f, 0.05f);\
    float z4n = izh(vI, uI, z3h * a6,                     0.25f, -65.f, 6.f);  \
    float z5n = izh(vT, uT, w9c * (z3h * a8) + w10c * z5h1, 0.20f, -50.f, 2.f);\
    float z6n = izh(vM, uM, z5h2 * a11,                   0.25f, -65.f, 6.f);  \
    l0[K][lane] = z6n; l1[K][lane] = vM;                                       \
    if (ch == 0) { l4[K][lane] = P4_d2; l5[K][lane] = P5_d2; }                 \
    P4_d2 = P4_d1; P4_d1 = make_float4(z2h2, z3h, z4n, z5n);                   \
    P5_d2 = P5_d1; P5_d1 = make_float4(vLh, vEp, vI, vT);                      \
    z2h2 = zLs; zL = z2n; zph = zpc; z3h = z3n;                                \
    z5h2 = z5h1; z5h1 = z5n; vLh = vLp; }

    // ---------------- warm-up j = 0..3 (no stores; t=j-4 < 0) ----------------
    float4 s0 = S4[0];
    {   // j=0: L(0)
        float zpc = s0.x * a0;
        float zLs = zL, vLp = vL;
        float z2n = izh(vL, uL, w2c * (zpc * a1) + w3c * zLs, 0.20f, -65.f, 6.f);
        z2h2 = zLs; zL = z2n; zph = zpc; vLh = vLp;
    }
    {   // j=1: L(1), E(0)
        float zpc = s0.y * a0;
        float zLs = zL, vLp = vL;
        float z2n = izh(vL, uL, w2c * (zpc * a1) + w3c * zLs, 0.20f, -65.f, 6.f);
        float z3n = izh(vE, uE, zph * a4 + zLs * a5,          0.25f, -55.f, 0.05f);
        z2h2 = zLs; zL = z2n; zph = zpc; z3h = z3n; vLh = vLp;
    }
    {   // j=2: L(2), E(1), I(0), T(0); build P4_d1/P5_d1 for t=0
        float zpc = s0.z * a0;
        float zLs = zL, vLp = vL, vEp = vE;
        float z2n = izh(vL, uL, w2c * (zpc * a1) + w3c * zLs,   0.20f, -65.f, 6.f);
        float z3n = izh(vE, uE, zph * a4 + zLs * a5,            0.25f, -55.f, 0.05f);
        float z4n = izh(vI, uI, z3h * a6,                       0.25f, -65.f, 6.f);
        float z5n = izh(vT, uT, w9c * (z3h * a8) + w10c * z5h1, 0.20f, -50.f, 2.f);
        P4_d1 = make_float4(z2h2, z3h, z4n, z5n);
        P5_d1 = make_float4(vLh, vEp, vI, vT);
        z2h2 = zLs; zL = z2n; zph = zpc; z3h = z3n;
        z5h2 = z5h1; z5h1 = z5n; vLh = vLp;
    }
    {   // j=3: L(3), E(2), I(1), T(1); shift, build t=1
        float zpc = s0.w * a0;
        float zLs = zL, vLp = vL, vEp = vE;
        float z2n = izh(vL, uL, w2c * (zpc * a1) + w3c * zLs,   0.20f, -65.f, 6.f);
        float z3n = izh(vE, uE, zph * a4 + zLs * a5,            0.25f, -55.f, 0.05f);
        float z4n = izh(vI, uI, z3h * a6,                       0.25f, -65.f, 6.f);
        float z5n = izh(vT, uT, w9c * (z3h * a8) + w10c * z5h1, 0.20f, -50.f, 2.f);
        P4_d2 = P4_d1; P4_d1 = make_float4(z2h2, z3h, z4n, z5n);
        P5_d2 = P5_d1; P5_d1 = make_float4(vLh, vEp, vI, vT);
        z2h2 = zLs; zL = z2n; zph = zpc; z3h = z3n;
        z5h2 = z5h1; z5h1 = z5n; vLh = vLp;
    }

    // ---------------- main: 31 tiles x 16 iters, j = 4..499, t = 0..495 ------
    float4 cur0 = S4[1], cur1 = S4[2], cur2 = S4[3], cur3 = S4[4];
    for (int ti = 0; ti < 31; ++ti) {
        float4 n0 = cur0, n1 = cur1, n2 = cur2, n3 = cur3;
        if (ti < 30) {
            n0 = S4[4 * ti + 5]; n1 = S4[4 * ti + 6];
            n2 = S4[4 * ti + 7]; n3 = S4[4 * ti + 8];
        }
        FULL_ITER(cur0.x, 0)  FULL_ITER(cur0.y, 1)  FULL_ITER(cur0.z, 2)  FULL_ITER(cur0.w, 3)
        FULL_ITER(cur1.x, 4)  FULL_ITER(cur1.y, 5)  FULL_ITER(cur1.z, 6)  FULL_ITER(cur1.w, 7)
        FULL_ITER(cur2.x, 8)  FULL_ITER(cur2.y, 9)  FULL_ITER(cur2.z, 10) FULL_ITER(cur2.w, 11)
        FULL_ITER(cur3.x, 12) FULL_ITER(cur3.y, 13) FULL_ITER(cur3.z, 14) FULL_ITER(cur3.w, 15)
        __syncthreads();

        // ---- dump tile (t0 = 16*ti), fully coalesced ----
        const int t0 = 16 * ti;
        {
            const int r = lane >> 2, f = lane & 3;
#pragma unroll
            for (int jj = 0; jj < 4; ++jj) {
                const int row = jj * 16 + r;
                const size_t g = (size_t)(brow + row) * T_ + t0 + 4 * f;
                *(float4*)&q0base[g] = make_float4(l0[4*f+0][row], l0[4*f+1][row],
                                                   l0[4*f+2][row], l0[4*f+3][row]);
                *(float4*)&q1base[g] = make_float4(l1[4*f+0][row], l1[4*f+1][row],
                                                   l1[4*f+2][row], l1[4*f+3][row]);
            }
        }
        if (ch == 0) {
            const int r2 = lane >> 4, tt = lane & 15;
#pragma unroll
            for (int jj = 0; jj < 16; ++jj) {
                const int row = jj * 4 + r2;
                const size_t g = (size_t)(brow + row) * T_ + t0 + tt;
                p4base[g] = l4[tt][row];
                p5base[g] = l5[tt][row];
            }
        }
        __syncthreads();
        cur0 = n0; cur1 = n1; cur2 = n2; cur3 = n3;
    }

    // ---------------- tail: j = 500..503, t = 496..499, direct stores --------
    float* q0d = q0base + (size_t)b * T_;
    float* q1d = q1base + (size_t)b * T_;
    float4* p4d = p4base + (size_t)b * T_;
    float4* p5d = p5base + (size_t)b * T_;
    {   // j=500: E(499), I(498), T(498), M(496)
        float zLs = zL, vEp = vE;
        float z3n = izh(vE, uE, zph * a4 + zLs * a5,            0.25f, -55.f, 0.05f);
        float z4n = izh(vI, uI, z3h * a6,                       0.25f, -65.f, 6.f);
        float z5n = izh(vT, uT, w9c * (z3h * a8) + w10c * z5h1, 0.20f, -50.f, 2.f);
        float z6n = izh(vM, uM, z5h2 * a11,                     0.25f, -65.f, 6.f);
        q0d[496] = z6n; q1d[496] = vM;
        if (ch == 0) { p4d[496] = P4_d2; p5d[496] = P5_d2; }
        P4_d2 = P4_d1; P4_d1 = make_float4(z2h2, z3h, z4n, z5n);   // t=498
        P5_d2 = P5_d1; P5_d1 = make_float4(vLh, vEp, vI, vT);
        z2h2 = zLs; z3h = z3n; z5h2 = z5h1; z5h1 = z5n; vLh = vL;
    }
    {   // j=501: I(499), T(499), M(497)
        float vEp = vE;
        float z4n = izh(vI, uI, z3h * a6,                       0.25f, -65.f, 6.f);
        float z5n = izh(vT, uT, w9c * (z3h * a8) + w10c * z5h1, 0.20f, -50.f, 2.f);
        float z6n = izh(vM, uM, z5h2 * a11,                     0.25f, -65.f, 6.f);
        q0d[497] = z6n; q1d[497] = vM;
        if (ch == 0) { p4d[497] = P4_d2; p5d[497] = P5_d2; }
        P4_d2 = P4_d1; P4_d1 = make_float4(z2h2, z3h, z4n, z5n);   // t=499
        P5_d2 = P5_d1; P5_d1 = make_float4(vLh, vEp, vI, vT);
        z5h2 = z5h1; z5h1 = z5n;
    }
    {   // j=502: M(498)
        float z6n = izh(vM, uM, z5h2 * a11,                     0.25f, -65.f, 6.f);
        q0d[498] = z6n; q1d[498] = vM;
        if (ch == 0) { p4d[498] = P4_d2; p5d[498] = P5_d2; }
        P4_d2 = P4_d1; P5_d2 = P5_d1;
        z5h2 = z5h1;
    }
    {   // j=503: M(499)
        float z6n = izh(vM, uM, z5h2 * a11,                     0.25f, -65.f, 6.f);
        q0d[499] = z6n; q1d[499] = vM;
        if (ch == 0) { p4d[499] = P4_d2; p5d[499] = P5_d2; }
    }
#undef FULL_ITER
}

// ---------------------------------------------------------------------------
// Fallback (tiny ws): both channels in one thread, S aliasing out's o_spikes
// region (per-thread reads strictly lead writes; no restrict -> order kept).
// ---------------------------------------------------------------------------
__global__ __launch_bounds__(64) void scan_kernel_alias(const float* S,
                                                        const float* __restrict__ w24,
                                                        float* out) {
    int b = blockIdx.x * 64 + threadIdx.x;
    if (b >= B_) return;

    const float w0 = w24[0],  w1 = w24[1],  w2 = w24[2],  w3 = w24[3];
    const float w4 = w24[4],  w5 = w24[5],  w6 = w24[6];
    const float w8 = w24[8],  w9 = w24[9],  w10 = w24[10], w11 = w24[11];
    const float w12 = w24[12], w13 = w24[13], w16 = w24[16], w17 = w24[17];
    const float w18 = w24[18], w20 = w24[20], w23 = w24[23];

    float vL = -70.f, uL = -14.f, zL = 0.f;
    float vE = -64.f, uE = -16.f;
    float vI = -64.f, uI = -16.f;
    float vT = -70.f, uT = -14.f, zT = 0.f;
    float vM = -64.f, uM = -16.f;
    float vL2 = -70.f, uL2 = -14.f, zL2 = 0.f;
    float vE2 = -64.f, uE2 = -16.f;
    float vI2 = -64.f, uI2 = -16.f;
    float vT2 = -70.f, uT2 = -14.f, zT2 = 0.f;
    float vM2 = -64.f, uM2 = -16.f;

    const float4* Srow = (const float4*)(S + (size_t)b * T_);
    float* p0 = out + (size_t)b * T_;
    float* p1 = p0 + (size_t)BT;
    float* p2 = p0 + (size_t)2 * BT;
    float* p3 = p0 + (size_t)3 * BT;
    float4* p4 = (float4*)out + (size_t)BT + (size_t)b * T_;
    float4* p5 = (float4*)out + (size_t)2 * BT + (size_t)b * T_;

    float4 sc = Srow[0];
    for (int i = 0; i < T_ / 4; ++i) {
        float4 sn = sc;
        if (i + 1 < T_ / 4) sn = Srow[i + 1];
        float sv[4] = {sc.x, sc.y, sc.z, sc.w};
#pragma unroll
        for (int k = 0; k < 4; ++k) {
            int t = 4 * i + k;
            float Ssum = sv[k];
            float zp  = Ssum * w0;
            float zp2 = Ssum * w12;
            float z2 = izh(vL, uL, w2 * (zp * w1) + w3 * zL, 0.20f, -65.f, 6.f);
            float z3 = izh(vE, uE, zp * w4 + z2 * w5,        0.25f, -55.f, 0.05f);
            float z4 = izh(vI, uI, z3 * w6,                  0.25f, -65.f, 6.f);
            float z5 = izh(vT, uT, w9 * (z3 * w8) + w10 * zT,0.20f, -50.f, 2.f);
            float z6 = izh(vM, uM, z5 * w11,                 0.25f, -65.f, 6.f);
            zL = z2; zT = z5;
            float z22 = izh(vL2, uL2, w2 * (zp2 * w13) + w3 * zL2, 0.20f, -65.f, 6.f);
            float z32 = izh(vE2, uE2, zp2 * w16 + z22 * w17,       0.25f, -55.f, 0.05f);
            float z42 = izh(vI2, uI2, z32 * w18,                   0.25f, -65.f, 6.f);
            float z52 = izh(vT2, uT2, w9 * (z32 * w20) + w10 * zT2,0.20f, -50.f, 2.f);
            float z62 = izh(vM2, uM2, z52 * w23,                   0.25f, -65.f, 6.f);
            zL2 = z22; zT2 = z52;
            (void)z42;

            p0[t] = z6;
            p1[t] = vM;
            p2[t] = z62;
            p3[t] = vM2;
            p4[t] = make_float4(z2, z3, z4, z5);
            p5[t] = make_float4(vL, vE, vI, vT);
        }
        sc = sn;
    }
}

extern "C" void kernel_launch(void* const* d_in, const int* in_sizes, int n_in,
                              void* d_out, int out_size, void* d_ws, size_t ws_size,
                              hipStream_t stream) {
    const float* in = (const float*)d_in[0];
    const float* w  = (const float*)d_in[1];
    float* out = (float*)d_out;

    bool use_ws = ws_size >= (size_t)BT * sizeof(float);
    float* S = use_ws ? (float*)d_ws : out;

    rowsum_kernel<<<(BT * 16) / 256, 256, 0, stream>>>(in, S);

    if (use_ws) {
        scan_pipe_lds_kernel<<<64, 64, 0, stream>>>(S, w, out);
    } else {
        scan_kernel_alias<<<(B_ + 63) / 64, 64, 0, stream>>>(S, w, out);
    }
}

// Round 7
// 111.263 us; speedup vs baseline: 1.4540x; 1.4540x over previous
//
#include <hip/hip_runtime.h>

#define B_ 2048
#define T_ 500
#define N_ 64
#define BT (B_ * T_)

// ---------------------------------------------------------------------------
// Kernel 1: row sums.  S[r] = sum_n input[r*64 + n],  r = b*T + t.
// 16 lanes cooperate per row; fully coalesced 1 KB/wave loads. HBM roofline.
// ---------------------------------------------------------------------------
__global__ __launch_bounds__(256) void rowsum_kernel(const float* __restrict__ in,
                                                     float* __restrict__ S) {
    long long gid = (long long)blockIdx.x * 256 + threadIdx.x;  // chunk index
    const float4* p = (const float4*)in;
    float4 v = p[gid];
    float s = (v.x + v.y) + (v.z + v.w);
    s += __shfl_xor(s, 1);
    s += __shfl_xor(s, 2);
    s += __shfl_xor(s, 4);
    s += __shfl_xor(s, 8);
    if ((threadIdx.x & 15) == 0) S[gid >> 4] = s;
}

// ---------------------------------------------------------------------------
// Izhikevich Euler step — association order matches the reference exactly.
// ---------------------------------------------------------------------------
__device__ __forceinline__ float izh(float& v, float& u, float I,
                                     float b, float c, float d) {
    float t  = 0.04f * v * v + 5.0f * v + 140.0f - u + I;
    float v_ = v + 0.25f * t;
    float u_ = u + 0.005f * (b * v - u);
    float z  = (v_ >= 30.0f) ? 1.0f : 0.0f;
    v = (v_ >= 30.0f) ? c : v_;
    u = u_ + z * d;
    return z;
}

// Masked variant: invalid lanes hold state and emit z=0. Same float ops.
__device__ __forceinline__ float izh_m(float& v, float& u, float I,
                                       float b, float c, float d, bool valid) {
    float t  = 0.04f * v * v + 5.0f * v + 140.0f - u + I;
    float v_ = v + 0.25f * t;
    float u_ = u + 0.005f * (b * v - u);
    float z  = (v_ >= 30.0f) ? 1.0f : 0.0f;
    float vn = (v_ >= 30.0f) ? c : v_;
    float un = u_ + z * d;
    if (!valid) { z = 0.f; vn = v; un = u; }
    v = vn; u = un;
    return z;
}

// ---------------------------------------------------------------------------
// Kernel 2: SYSTOLIC LANE-SPLIT scan. 8 lane-slots per chain (roles 0-4 =
// L,E,I,T,M; 5-7 idle), 8 chains per wave, 512 waves total (vs 64 before) —
// attacks the measured per-wave instruction-issue bound (~4-6 cyc/instr).
// Pipeline offsets: L computes step j, E j-1, I j-2, T j-2, M j-4; the one
// cross-neuron value per iter moves by a single __shfl. All lanes run the
// SAME generic izh with per-lane constants; source/delay selection is done
// with exact {0,1}-coefficient fma sums (all selected values >= 0, products
// with 0.0 give +0, and x+0 / 1*x are IEEE-exact -> bit-identical numerics).
// Outputs are delay-equalized to t=j-4, staged in a 16-step LDS tile, and
// dumped coalesced. Block = 1 wave, no barriers except the cheap 1-wave
// __syncthreads before each dump.
// ---------------------------------------------------------------------------
__global__ __launch_bounds__(64, 1) void scan_sys_kernel(const float* __restrict__ S,
                                                         const float* __restrict__ w24,
                                                         float* __restrict__ out) {
    // buf[s][c][12]: [0..7]=(z2,vL,z3,vE,z4,vI,z5,vT), [8,9]=(z6,vM), [10,11]=pad
    // s-stride padded to 100 floats so dump reads spread banks.
    __shared__ float buf[16 * 100];

    const int lane = threadIdx.x;
    const int c    = lane >> 3;        // chain slot 0..7
    const int role = lane & 7;         // 0..4 active, 5..7 idle
    const int ch   = (blockIdx.x >= 256) ? 1 : 0;   // uniform per block
    const int b    = (blockIdx.x * 8 + c) & (B_ - 1);

    const float a0  = ch ? w24[12] : w24[0];
    const float W1  = ch ? w24[13] : w24[1];
    const float W4  = ch ? w24[16] : w24[4];
    const float W5  = ch ? w24[17] : w24[5];
    const float W6  = ch ? w24[18] : w24[6];
    const float W8  = ch ? w24[20] : w24[8];
    const float W11 = ch ? w24[23] : w24[11];
    const float W2 = w24[2], W3 = w24[3], W9 = w24[9], W10 = w24[10];

    float pb, pc, pd, v, u;
    float wA, wB, wC, wD;
    float fL = 0.f, fE = 0.f, fIT = 0.f, fM = 0.f;   // X-source select
    float cL = 0.f, cE = 0.f, cIT = 0.f, cM = 0.f;   // store-delay select
    int offs, srcRole, pairOff;
    if (role == 0) {        // LLBN: I = w2*(zp*w1) + w3*z2(self,prev)
        pb = 0.20f; pc = -65.f; pd = 6.f;   v = -70.f; u = -14.f;
        wA = W2; wB = W1; wC = 0.f; wD = W3;
        offs = 0; srcRole = 0; fL = 1.f; cL = 1.f; pairOff = 0;
    } else if (role == 1) { // EBN: I = zp*w4 + z2*w5
        pb = 0.25f; pc = -55.f; pd = 0.05f; v = -64.f; u = -16.f;
        wA = 1.f; wB = W4; wC = W5; wD = 0.f;
        offs = 1; srcRole = 0; fE = 1.f; cE = 1.f; pairOff = 2;
    } else if (role == 2) { // IFN: I = z3*w6
        pb = 0.25f; pc = -65.f; pd = 6.f;   v = -64.f; u = -16.f;
        wA = 1.f; wB = W6; wC = 0.f; wD = 0.f;
        offs = 2; srcRole = 1; fIT = 1.f; cIT = 1.f; pairOff = 4;
    } else if (role == 3) { // TN: I = w9*(z3*w8) + w10*z5(self,prev)
        pb = 0.20f; pc = -50.f; pd = 2.f;   v = -70.f; u = -14.f;
        wA = W9; wB = W8; wC = 0.f; wD = W10;
        offs = 2; srcRole = 1; fIT = 1.f; cIT = 1.f; pairOff = 6;
    } else if (role == 4) { // MN: I = z5*w11
        pb = 0.25f; pc = -65.f; pd = 6.f;   v = -64.f; u = -16.f;
        wA = 1.f; wB = W11; wC = 0.f; wD = 0.f;
        offs = 4; srcRole = 3; fM = 1.f; cM = 1.f; pairOff = 8;
    } else {                // idle: zero inputs, bounded dynamics, writes to pad
        pb = 0.25f; pc = -65.f; pd = 6.f;   v = -64.f; u = -16.f;
        wA = 0.f; wB = 0.f; wC = 0.f; wD = 0.f;
        offs = 7; srcRole = 0; pairOff = 10;
    }
    const int srcLane = (c << 3) | srcRole;
    float* lds = &buf[c * 12 + pairOff];

    float* q0g = out + (size_t)(ch ? 2 : 0) * BT;   // o_spikes / o_spikes2
    float* q1g = out + (size_t)(ch ? 3 : 1) * BT;   // v / v2
    float4* p4g = (float4*)out + (size_t)BT;        // o_spikes_o (float4 idx)
    float4* p5g = (float4*)out + (size_t)2 * BT;    // v_o
    const int bD0 = (blockIdx.x * 8 + (lane >> 4)) & (B_ - 1);
    const int bD1 = (blockIdx.x * 8 + (lane >> 4) + 4) & (B_ - 1);

    float z_last = 0.f, in0 = 0.f, in1 = 0.f, zp_cur = 0.f, zp_prev = 0.f;
    float zd1 = 0.f, zd2 = 0.f, zd3 = 0.f, zd4 = 0.f;
    float vd1 = v, vd2 = v, vd3 = v, vd4 = v;

    const float4* S4 = (const float4*)(S + (size_t)b * T_);

#define SYS_ITER(SV, DOSTORE, SLOT, VEXPR) {                                   \
    in1 = in0;                                                                 \
    in0 = __shfl(z_last, srcLane, 64);                                         \
    zp_prev = zp_cur;                                                          \
    zp_cur  = (SV) * a0;                                                       \
    float X = ((fL * zp_cur + fE * zp_prev) + fIT * in0) + fM * in1;           \
    float Isyn = wA * (X * wB) + wC * in0 + wD * z_last;                       \
    bool valid = (VEXPR);                                                      \
    float znew = izh_m(v, u, Isyn, pb, pc, pd, valid);                         \
    if (DOSTORE) {                                                             \
        float zst = ((cL * zd4 + cE * zd3) + cIT * zd2) + cM * znew;           \
        float vst = ((cL * vd4 + cE * vd3) + cIT * vd2) + cM * v;              \
        *(float2*)(lds + (SLOT) * 100) = make_float2(zst, vst);                \
    }                                                                          \
    zd4 = zd3; zd3 = zd2; zd2 = zd1; zd1 = znew;                               \
    vd4 = vd3; vd3 = vd2; vd2 = vd1; vd1 = v;                                  \
    z_last = znew;                                                             \
}

#define DUMP(T0, LIM) {                                                        \
    __syncthreads();                                                           \
    const int sD = lane & 15;                                                  \
    if ((LIM) == 16 || sD < (LIM)) {                                           \
        const int c20 = lane >> 4;                                             \
        const float* r0 = &buf[sD * 100 + c20 * 12];                           \
        const float* r1 = &buf[sD * 100 + (c20 + 4) * 12];                     \
        float4 A0 = *(const float4*)&r0[0];                                    \
        float4 B0 = *(const float4*)&r0[4];                                    \
        float2 C0 = *(const float2*)&r0[8];                                    \
        float4 A1 = *(const float4*)&r1[0];                                    \
        float4 B1 = *(const float4*)&r1[4];                                    \
        float2 C1 = *(const float2*)&r1[8];                                    \
        size_t g0 = (size_t)bD0 * T_ + (T0) + sD;                              \
        size_t g1 = (size_t)bD1 * T_ + (T0) + sD;                              \
        q0g[g0] = C0.x; q1g[g0] = C0.y;                                        \
        q0g[g1] = C1.x; q1g[g1] = C1.y;                                        \
        if (ch == 0) {                                                         \
            p4g[g0] = make_float4(A0.x, A0.z, B0.x, B0.z);                     \
            p5g[g0] = make_float4(A0.y, A0.w, B0.y, B0.w);                     \
            p4g[g1] = make_float4(A1.x, A1.z, B1.x, B1.z);                     \
            p5g[g1] = make_float4(A1.y, A1.w, B1.y, B1.w);                     \
        }                                                                      \
    }                                                                          \
}

    // ---- prologue: j = 0..3, no stores (t = j-4 < 0) ----
    float4 sg = S4[0];
    SYS_ITER(sg.x, 0, 0, (offs <= 0))
    SYS_ITER(sg.y, 0, 0, (offs <= 1))
    SYS_ITER(sg.z, 0, 0, (offs <= 2))
    SYS_ITER(sg.w, 0, 0, (offs <= 3))

    // ---- main: 31 tiles x 16 iters, j = 4..499, stores t = 0..495 ----
    float4 g0 = S4[1], g1 = S4[2], g2 = S4[3], g3 = S4[4];
    for (int k = 0; k < 31; ++k) {
        float4 n0 = g0, n1 = g1, n2 = g2, n3 = g3;
        if (k < 30) {   // prefetch next tile's S (consumed ~16 iters later)
            n0 = S4[4 * k + 5]; n1 = S4[4 * k + 6];
            n2 = S4[4 * k + 7]; n3 = S4[4 * k + 8];
        }
        SYS_ITER(g0.x, 1, 0,  true) SYS_ITER(g0.y, 1, 1,  true)
        SYS_ITER(g0.z, 1, 2,  true) SYS_ITER(g0.w, 1, 3,  true)
        SYS_ITER(g1.x, 1, 4,  true) SYS_ITER(g1.y, 1, 5,  true)
        SYS_ITER(g1.z, 1, 6,  true) SYS_ITER(g1.w, 1, 7,  true)
        SYS_ITER(g2.x, 1, 8,  true) SYS_ITER(g2.y, 1, 9,  true)
        SYS_ITER(g2.z, 1, 10, true) SYS_ITER(g2.w, 1, 11, true)
        SYS_ITER(g3.x, 1, 12, true) SYS_ITER(g3.y, 1, 13, true)
        SYS_ITER(g3.z, 1, 14, true) SYS_ITER(g3.w, 1, 15, true)
        DUMP(16 * k, 16)
        g0 = n0; g1 = n1; g2 = n2; g3 = n3;
    }

    // ---- epilogue: j = 500..503, stores t = 496..499 ----
    __syncthreads();
    SYS_ITER(0.f, 1, 0, (offs >= 1))
    SYS_ITER(0.f, 1, 1, (offs >= 2))
    SYS_ITER(0.f, 1, 2, (offs >= 3))
    SYS_ITER(0.f, 1, 3, (offs >= 4))
    DUMP(496, 4)

#undef SYS_ITER
#undef DUMP
}

// ---------------------------------------------------------------------------
// Fallback (tiny ws): both channels in one thread, S aliasing out's o_spikes
// region (per-thread reads strictly lead writes; no restrict -> order kept).
// ---------------------------------------------------------------------------
__global__ __launch_bounds__(64) void scan_kernel_alias(const float* S,
                                                        const float* __restrict__ w24,
                                                        float* out) {
    int b = blockIdx.x * 64 + threadIdx.x;
    if (b >= B_) return;

    const float w0 = w24[0],  w1 = w24[1],  w2 = w24[2],  w3 = w24[3];
    const float w4 = w24[4],  w5 = w24[5],  w6 = w24[6];
    const float w8 = w24[8],  w9 = w24[9],  w10 = w24[10], w11 = w24[11];
    const float w12 = w24[12], w13 = w24[13], w16 = w24[16], w17 = w24[17];
    const float w18 = w24[18], w20 = w24[20], w23 = w24[23];

    float vL = -70.f, uL = -14.f, zL = 0.f;
    float vE = -64.f, uE = -16.f;
    float vI = -64.f, uI = -16.f;
    float vT = -70.f, uT = -14.f, zT = 0.f;
    float vM = -64.f, uM = -16.f;
    float vL2 = -70.f, uL2 = -14.f, zL2 = 0.f;
    float vE2 = -64.f, uE2 = -16.f;
    float vI2 = -64.f, uI2 = -16.f;
    float vT2 = -70.f, uT2 = -14.f, zT2 = 0.f;
    float vM2 = -64.f, uM2 = -16.f;

    const float4* Srow = (const float4*)(S + (size_t)b * T_);
    float* p0 = out + (size_t)b * T_;
    float* p1 = p0 + (size_t)BT;
    float* p2 = p0 + (size_t)2 * BT;
    float* p3 = p0 + (size_t)3 * BT;
    float4* p4 = (float4*)out + (size_t)BT + (size_t)b * T_;
    float4* p5 = (float4*)out + (size_t)2 * BT + (size_t)b * T_;

    float4 sc = Srow[0];
    for (int i = 0; i < T_ / 4; ++i) {
        float4 sn = sc;
        if (i + 1 < T_ / 4) sn = Srow[i + 1];
        float sv[4] = {sc.x, sc.y, sc.z, sc.w};
#pragma unroll
        for (int k = 0; k < 4; ++k) {
            int t = 4 * i + k;
            float Ssum = sv[k];
            float zp  = Ssum * w0;
            float zp2 = Ssum * w12;
            float z2 = izh(vL, uL, w2 * (zp * w1) + w3 * zL, 0.20f, -65.f, 6.f);
            float z3 = izh(vE, uE, zp * w4 + z2 * w5,        0.25f, -55.f, 0.05f);
            float z4 = izh(vI, uI, z3 * w6,                  0.25f, -65.f, 6.f);
            float z5 = izh(vT, uT, w9 * (z3 * w8) + w10 * zT,0.20f, -50.f, 2.f);
            float z6 = izh(vM, uM, z5 * w11,                 0.25f, -65.f, 6.f);
            zL = z2; zT = z5;
            float z22 = izh(vL2, uL2, w2 * (zp2 * w13) + w3 * zL2, 0.20f, -65.f, 6.f);
            float z32 = izh(vE2, uE2, zp2 * w16 + z22 * w17,       0.25f, -55.f, 0.05f);
            float z42 = izh(vI2, uI2, z32 * w18,                   0.25f, -65.f, 6.f);
            float z52 = izh(vT2, uT2, w9 * (z32 * w20) + w10 * zT2,0.20f, -50.f, 2.f);
            float z62 = izh(vM2, uM2, z52 * w23,                   0.25f, -65.f, 6.f);
            zL2 = z22; zT2 = z52;
            (void)z42;

            p0[t] = z6;
            p1[t] = vM;
            p2[t] = z62;
            p3[t] = vM2;
            p4[t] = make_float4(z2, z3, z4, z5);
            p5[t] = make_float4(vL, vE, vI, vT);
        }
        sc = sn;
    }
}

extern "C" void kernel_launch(void* const* d_in, const int* in_sizes, int n_in,
                              void* d_out, int out_size, void* d_ws, size_t ws_size,
                              hipStream_t stream) {
    const float* in = (const float*)d_in[0];
    const float* w  = (const float*)d_in[1];
    float* out = (float*)d_out;

    bool use_ws = ws_size >= (size_t)BT * sizeof(float);
    float* S = use_ws ? (float*)d_ws : out;

    rowsum_kernel<<<(BT * 16) / 256, 256, 0, stream>>>(in, S);

    if (use_ws) {
        // 512 blocks x 1 wave: blocks [0,256) = channel 1, [256,512) = ch 2.
        scan_sys_kernel<<<512, 64, 0, stream>>>(S, w, out);
    } else {
        scan_kernel_alias<<<(B_ + 63) / 64, 64, 0, stream>>>(S, w, out);
    }
}

// Round 8
// 103.799 us; speedup vs baseline: 1.5586x; 1.0719x over previous
//
#include <hip/hip_runtime.h>

#define B_ 2048
#define T_ 500
#define N_ 64
#define BT (B_ * T_)

// ---------------------------------------------------------------------------
// Kernel 1: row sums.  S[r] = sum_n input[r*64 + n],  r = b*T + t.
// 16 lanes cooperate per row; fully coalesced 1 KB/wave loads. HBM roofline.
// ---------------------------------------------------------------------------
__global__ __launch_bounds__(256) void rowsum_kernel(const float* __restrict__ in,
                                                     float* __restrict__ S) {
    long long gid = (long long)blockIdx.x * 256 + threadIdx.x;  // chunk index
    const float4* p = (const float4*)in;
    float4 v = p[gid];
    float s = (v.x + v.y) + (v.z + v.w);
    s += __shfl_xor(s, 1);
    s += __shfl_xor(s, 2);
    s += __shfl_xor(s, 4);
    s += __shfl_xor(s, 8);
    if ((threadIdx.x & 15) == 0) S[gid >> 4] = s;
}

// ---------------------------------------------------------------------------
// Izhikevich Euler step — association order matches the reference exactly.
// ---------------------------------------------------------------------------
__device__ __forceinline__ float izh(float& v, float& u, float I,
                                     float b, float c, float d) {
    float t  = 0.04f * v * v + 5.0f * v + 140.0f - u + I;
    float v_ = v + 0.25f * t;
    float u_ = u + 0.005f * (b * v - u);
    float z  = (v_ >= 30.0f) ? 1.0f : 0.0f;
    v = (v_ >= 30.0f) ? c : v_;
    u = u_ + z * d;
    return z;
}

// Masked variant: invalid lanes hold state and emit z=0. Same float ops.
__device__ __forceinline__ float izh_m(float& v, float& u, float I,
                                       float b, float c, float d, bool valid) {
    float t  = 0.04f * v * v + 5.0f * v + 140.0f - u + I;
    float v_ = v + 0.25f * t;
    float u_ = u + 0.005f * (b * v - u);
    float z  = (v_ >= 30.0f) ? 1.0f : 0.0f;
    float vn = (v_ >= 30.0f) ? c : v_;
    float un = u_ + z * d;
    if (!valid) { z = 0.f; vn = v; un = u; }
    v = vn; u = un;
    return z;
}

// ---------------------------------------------------------------------------
// Kernel 2: systolic lane-split scan, GAP-3 pipeline + LDS ring buffer.
// Roles (lane&7): 0=L, 1=E, 2=I, 3=T, 4=M, 5-7 idle. 8 chains/wave,
// 512 one-wave blocks. Pipeline offsets: L computes step j, E j-3, I/T j-6,
// M j-9 — every cross-neuron transfer has a 3-iteration producer->consumer
// gap, so the ds_bpermute (__shfl) is issued 1 iter after production and
// consumed 2 iters later: its ~120cyc latency is fully off the critical path.
// Each lane writes raw (znew, v) to a 32-deep LDS ring each iter; the per-16
// -step DUMP applies role time-offsets at read time (z2@t, z3@t+3, z4/z5@t+6,
// z6@t+9) and stores coalesced. No per-iter delay-equalization needed.
// ---------------------------------------------------------------------------
__global__ __launch_bounds__(64, 1) void scan_sys2_kernel(const float* __restrict__ S,
                                                          const float* __restrict__ w24,
                                                          float* __restrict__ out) {
    // ring[s][c][12]: per iter-slot s (mod 32), chain c: pairs at offset
    // 2*role: (z2,vL)(z3,vE)(z4,vI)(z5,vT)(z6,vM)(pad). s-stride 100 floats.
    __shared__ float ring_lds[32 * 100];

    const int lane = threadIdx.x;
    const int c    = lane >> 3;        // chain slot 0..7
    const int role = lane & 7;         // 0..4 active, 5..7 idle
    const int ch   = (blockIdx.x >= 256) ? 1 : 0;   // uniform per block
    const int bbase = (blockIdx.x & 255) * 8;
    const int b    = bbase + c;

    const float a0  = ch ? w24[12] : w24[0];
    const float W1  = ch ? w24[13] : w24[1];
    const float W4  = ch ? w24[16] : w24[4];
    const float W5  = ch ? w24[17] : w24[5];
    const float W6  = ch ? w24[18] : w24[6];
    const float W8  = ch ? w24[20] : w24[8];
    const float W11 = ch ? w24[23] : w24[11];
    const float W2 = w24[2], W3 = w24[3], W9 = w24[9], W10 = w24[10];

    float pb, pc, pd, v, u;
    float wA, wB, wC, wD;
    float fL = 0.f, fE = 0.f, fITM = 0.f;
    int offs, srcRole, pairOff;
    if (role == 0) {        // LLBN: I = w2*(zp*w1) + w3*z2(self, prev step)
        pb = 0.20f; pc = -65.f; pd = 6.f;   v = -70.f; u = -14.f;
        wA = W2; wB = W1; wC = 0.f; wD = W3;
        offs = 0; srcRole = 0; fL = 1.f; pairOff = 0;
    } else if (role == 1) { // EBN: I = zp*w4 + z2*w5
        pb = 0.25f; pc = -55.f; pd = 0.05f; v = -64.f; u = -16.f;
        wA = 1.f; wB = W4; wC = W5; wD = 0.f;
        offs = 3; srcRole = 0; fE = 1.f; pairOff = 2;
    } else if (role == 2) { // IFN: I = z3*w6
        pb = 0.25f; pc = -65.f; pd = 6.f;   v = -64.f; u = -16.f;
        wA = 1.f; wB = W6; wC = 0.f; wD = 0.f;
        offs = 6; srcRole = 1; fITM = 1.f; pairOff = 4;
    } else if (role == 3) { // TN: I = w9*(z3*w8) + w10*z5(self, prev step)
        pb = 0.20f; pc = -50.f; pd = 2.f;   v = -70.f; u = -14.f;
        wA = W9; wB = W8; wC = 0.f; wD = W10;
        offs = 6; srcRole = 1; fITM = 1.f; pairOff = 6;
    } else if (role == 4) { // MN: I = z5*w11
        pb = 0.25f; pc = -65.f; pd = 6.f;   v = -64.f; u = -16.f;
        wA = 1.f; wB = W11; wC = 0.f; wD = 0.f;
        offs = 9; srcRole = 3; fITM = 1.f; pairOff = 8;
    } else {                // idle: zero input, bounded dynamics, pad slot
        pb = 0.25f; pc = -65.f; pd = 6.f;   v = -64.f; u = -16.f;
        wA = 0.f; wB = 0.f; wC = 0.f; wD = 0.f;
        offs = 9; srcRole = 0; fITM = 0.f; pairOff = 10;
    }
    const int srcLane = (c << 3) | srcRole;

    float* q0g = out + (size_t)(ch ? 2 : 0) * BT;   // o_spikes / o_spikes2
    float* q1g = out + (size_t)(ch ? 3 : 1) * BT;   // v / v2
    float4* p4g = (float4*)out + (size_t)BT;        // o_spikes_o (float4 idx)
    float4* p5g = (float4*)out + (size_t)2 * BT;    // v_o

    float z_last = 0.f, in_p1 = 0.f, in_p2 = 0.f;
    float zp1 = 0.f, zp2 = 0.f, zp3 = 0.f;

    const float4* S4 = (const float4*)(S + (size_t)b * T_);

#define SYS_ITER(SV, VEXPR, I_) {                                              \
    float in0 = in_p2;                                                         \
    in_p2 = in_p1;                                                             \
    in_p1 = __shfl(z_last, srcLane, 64);                                       \
    float zpc = (SV) * a0;                                                     \
    float X = (fL * zpc + fE * zp3) + fITM * in0;                              \
    float Isyn = wA * (X * wB) + wC * in0 + wD * z_last;                       \
    float znew = izh_m(v, u, Isyn, pb, pc, pd, (VEXPR));                       \
    *(float2*)(ringp + (I_) * 100) = make_float2(znew, v);                     \
    zp3 = zp2; zp2 = zp1; zp1 = zpc;                                           \
    z_last = znew;                                                             \
}

#define GROUP16(VF)                                                            \
    SYS_ITER(g0.x, VF(0),  0)  SYS_ITER(g0.y, VF(1),  1)                       \
    SYS_ITER(g0.z, VF(2),  2)  SYS_ITER(g0.w, VF(3),  3)                       \
    SYS_ITER(g1.x, VF(4),  4)  SYS_ITER(g1.y, VF(5),  5)                       \
    SYS_ITER(g1.z, VF(6),  6)  SYS_ITER(g1.w, VF(7),  7)                       \
    SYS_ITER(g2.x, VF(8),  8)  SYS_ITER(g2.y, VF(9),  9)                       \
    SYS_ITER(g2.z, VF(10), 10) SYS_ITER(g2.w, VF(11), 11)                      \
    SYS_ITER(g3.x, VF(12), 12) SYS_ITER(g3.y, VF(13), 13)                      \
    SYS_ITER(g3.z, VF(14), 14) SYS_ITER(g3.w, VF(15), 15)

#define VF_PRO(i)  ((i) >= offs)
#define VF_MAIN(i) true
#define VF_EPI(i)  ((i) <= 3 + offs)

// Dump tile after group K: t in [16K-9, 16K+6] (clamped to [0,499]).
// Entry for iter j0 lives at ring slot j0&31; needed j0 = t..t+9, all within
// the last 24 iters -> inside the 32-deep window.
#define DUMP(K) {                                                              \
    __syncthreads();                                                           \
    const int t = 16 * (K) - 9 + (lane & 15);                                  \
    if (0 <= t && t <= 499) {                                                  \
        const int c0 = lane >> 4;                                              \
        {                                                                      \
            const int cc = c0;                                                 \
            const float* rb = ring_lds + cc * 12;                              \
            float2 e2 = *(const float2*)&rb[((t + 9) & 31) * 100 + 8];         \
            size_t g = (size_t)(bbase + cc) * T_ + t;                          \
            q0g[g] = e2.x; q1g[g] = e2.y;                                      \
            if (ch == 0) {                                                     \
                float2 a2 = *(const float2*)&rb[(t & 31) * 100 + 0];           \
                float2 b2 = *(const float2*)&rb[((t + 3) & 31) * 100 + 2];     \
                float4 c4 = *(const float4*)&rb[((t + 6) & 31) * 100 + 4];     \
                p4g[g] = make_float4(a2.x, b2.x, c4.x, c4.z);                  \
                p5g[g] = make_float4(a2.y, b2.y, c4.y, c4.w);                  \
            }                                                                  \
        }                                                                      \
        {                                                                      \
            const int cc = c0 + 4;                                             \
            const float* rb = ring_lds + cc * 12;                              \
            float2 e2 = *(const float2*)&rb[((t + 9) & 31) * 100 + 8];         \
            size_t g = (size_t)(bbase + cc) * T_ + t;                          \
            q0g[g] = e2.x; q1g[g] = e2.y;                                      \
            if (ch == 0) {                                                     \
                float2 a2 = *(const float2*)&rb[(t & 31) * 100 + 0];           \
                float2 b2 = *(const float2*)&rb[((t + 3) & 31) * 100 + 2];     \
                float4 c4 = *(const float4*)&rb[((t + 6) & 31) * 100 + 4];     \
                p4g[g] = make_float4(a2.x, b2.x, c4.x, c4.z);                  \
                p5g[g] = make_float4(a2.y, b2.y, c4.y, c4.w);                  \
            }                                                                  \
        }                                                                      \
    }                                                                          \
    __syncthreads();                                                           \
}

    float4 g0 = S4[0], g1 = S4[1], g2 = S4[2], g3 = S4[3];
    float4 n0, n1, n2, n3;

    {   // group k = 0 (iters 0..15, validity ramp-up)
        n0 = S4[4]; n1 = S4[5]; n2 = S4[6]; n3 = S4[7];
        float* ringp = ring_lds + c * 12 + pairOff;
        GROUP16(VF_PRO)
        DUMP(0)
        g0 = n0; g1 = n1; g2 = n2; g3 = n3;
    }
    for (int k = 1; k <= 30; ++k) {   // groups 1..30 (iters 16..495, all valid)
        if (k < 30) {
            n0 = S4[4 * k + 4]; n1 = S4[4 * k + 5];
            n2 = S4[4 * k + 6]; n3 = S4[4 * k + 7];
        } else {
            n0 = S4[124];   // S[496..499]
            n1 = make_float4(0.f, 0.f, 0.f, 0.f);
            n2 = n1; n3 = n1;
        }
        float* ringp = ring_lds + (k & 1) * 1600 + c * 12 + pairOff;
        GROUP16(VF_MAIN)
        DUMP(k)
        g0 = n0; g1 = n1; g2 = n2; g3 = n3;
    }
    {   // group k = 31 (iters 496..511, validity ramp-down)
        float* ringp = ring_lds + 1600 + c * 12 + pairOff;
        GROUP16(VF_EPI)
        DUMP(31)
    }

#undef SYS_ITER
#undef GROUP16
#undef VF_PRO
#undef VF_MAIN
#undef VF_EPI
#undef DUMP
}

// ---------------------------------------------------------------------------
// Fallback (tiny ws): both channels in one thread, S aliasing out's o_spikes
// region (per-thread reads strictly lead writes; no restrict -> order kept).
// ---------------------------------------------------------------------------
__global__ __launch_bounds__(64) void scan_kernel_alias(const float* S,
                                                        const float* __restrict__ w24,
                                                        float* out) {
    int b = blockIdx.x * 64 + threadIdx.x;
    if (b >= B_) return;

    const float w0 = w24[0],  w1 = w24[1],  w2 = w24[2],  w3 = w24[3];
    const float w4 = w24[4],  w5 = w24[5],  w6 = w24[6];
    const float w8 = w24[8],  w9 = w24[9],  w10 = w24[10], w11 = w24[11];
    const float w12 = w24[12], w13 = w24[13], w16 = w24[16], w17 = w24[17];
    const float w18 = w24[18], w20 = w24[20], w23 = w24[23];

    float vL = -70.f, uL = -14.f, zL = 0.f;
    float vE = -64.f, uE = -16.f;
    float vI = -64.f, uI = -16.f;
    float vT = -70.f, uT = -14.f, zT = 0.f;
    float vM = -64.f, uM = -16.f;
    float vL2 = -70.f, uL2 = -14.f, zL2 = 0.f;
    float vE2 = -64.f, uE2 = -16.f;
    float vI2 = -64.f, uI2 = -16.f;
    float vT2 = -70.f, uT2 = -14.f, zT2 = 0.f;
    float vM2 = -64.f, uM2 = -16.f;

    const float4* Srow = (const float4*)(S + (size_t)b * T_);
    float* p0 = out + (size_t)b * T_;
    float* p1 = p0 + (size_t)BT;
    float* p2 = p0 + (size_t)2 * BT;
    float* p3 = p0 + (size_t)3 * BT;
    float4* p4 = (float4*)out + (size_t)BT + (size_t)b * T_;
    float4* p5 = (float4*)out + (size_t)2 * BT + (size_t)b * T_;

    float4 sc = Srow[0];
    for (int i = 0; i < T_ / 4; ++i) {
        float4 sn = sc;
        if (i + 1 < T_ / 4) sn = Srow[i + 1];
        float sv[4] = {sc.x, sc.y, sc.z, sc.w};
#pragma unroll
        for (int k = 0; k < 4; ++k) {
            int t = 4 * i + k;
            float Ssum = sv[k];
            float zp  = Ssum * w0;
            float zp2 = Ssum * w12;
            float z2 = izh(vL, uL, w2 * (zp * w1) + w3 * zL, 0.20f, -65.f, 6.f);
            float z3 = izh(vE, uE, zp * w4 + z2 * w5,        0.25f, -55.f, 0.05f);
            float z4 = izh(vI, uI, z3 * w6,                  0.25f, -65.f, 6.f);
            float z5 = izh(vT, uT, w9 * (z3 * w8) + w10 * zT,0.20f, -50.f, 2.f);
            float z6 = izh(vM, uM, z5 * w11,                 0.25f, -65.f, 6.f);
            zL = z2; zT = z5;
            float z22 = izh(vL2, uL2, w2 * (zp2 * w13) + w3 * zL2, 0.20f, -65.f, 6.f);
            float z32 = izh(vE2, uE2, zp2 * w16 + z22 * w17,       0.25f, -55.f, 0.05f);
            float z42 = izh(vI2, uI2, z32 * w18,                   0.25f, -65.f, 6.f);
            float z52 = izh(vT2, uT2, w9 * (z32 * w20) + w10 * zT2,0.20f, -50.f, 2.f);
            float z62 = izh(vM2, uM2, z52 * w23,                   0.25f, -65.f, 6.f);
            zL2 = z22; zT2 = z52;
            (void)z42;

            p0[t] = z6;
            p1[t] = vM;
            p2[t] = z62;
            p3[t] = vM2;
            p4[t] = make_float4(z2, z3, z4, z5);
            p5[t] = make_float4(vL, vE, vI, vT);
        }
        sc = sn;
    }
}

extern "C" void kernel_launch(void* const* d_in, const int* in_sizes, int n_in,
                              void* d_out, int out_size, void* d_ws, size_t ws_size,
                              hipStream_t stream) {
    const float* in = (const float*)d_in[0];
    const float* w  = (const float*)d_in[1];
    float* out = (float*)d_out;

    bool use_ws = ws_size >= (size_t)BT * sizeof(float);
    float* S = use_ws ? (float*)d_ws : out;

    rowsum_kernel<<<(BT * 16) / 256, 256, 0, stream>>>(in, S);

    if (use_ws) {
        // 512 blocks x 1 wave: blocks [0,256) = channel 1, [256,512) = ch 2.
        scan_sys2_kernel<<<512, 64, 0, stream>>>(S, w, out);
    } else {
        scan_kernel_alias<<<(B_ + 63) / 64, 64, 0, stream>>>(S, w, out);
    }
}

// Round 9
// 79.304 us; speedup vs baseline: 2.0400x; 1.3089x over previous
//
#include <hip/hip_runtime.h>

#define B_ 2048
#define T_ 500
#define BT (B_ * T_)

// ---------------------------------------------------------------------------
// Masked Izhikevich Euler step — association order matches the reference
// exactly (DT=0.25, all a=0.02 -> DT*a = 0.005f). Invalid lanes hold state.
// ---------------------------------------------------------------------------
__device__ __forceinline__ float izh_m(float& v, float& u, float I,
                                       float b, float c, float d, bool valid) {
    float t  = 0.04f * v * v + 5.0f * v + 140.0f - u + I;
    float v_ = v + 0.25f * t;
    float u_ = u + 0.005f * (b * v - u);
    float z  = (v_ >= 30.0f) ? 1.0f : 0.0f;
    float vn = (v_ >= 30.0f) ? c : v_;
    float un = u_ + z * d;
    if (!valid) { z = 0.f; vn = v; un = u; }
    v = vn; u = un;
    return z;
}

// ---------------------------------------------------------------------------
// FUSED producer-consumer kernel. 512 blocks x 192 threads (3 waves):
//   wave 0  = scanner: gap-3 systolic pipeline (L@j, E@j-3, I/T@j-6, M@j-9),
//             4 chains x 16 slots (slots 0-4 ch1 roles, 8-12 ch2 roles).
//   waves 1-2 = loaders: read next 16-step input tile (coalesced dwordx4),
//             shfl-reduce row sums (byte-identical order to the old rowsum
//             kernel), write into double-buffered S_lds.
// One uniform __syncthreads per group. The 262 MB input read fully overlaps
// the issue-bound scan. Ring: 6 (z,v) pairs/chain (ch1 L,E,I,T,M + ch2 M).
// ---------------------------------------------------------------------------
__global__ __launch_bounds__(192) void fused_scan_kernel(
        const float* __restrict__ in, const float* __restrict__ w24,
        float* __restrict__ out) {
    __shared__ float S_lds[128];       // [2 bufs][4 rows][16 tt]
    __shared__ float ring[32 * 56];    // [32 slots][4 chains * 14 floats]

    const int tid   = threadIdx.x;
    const int wid   = tid >> 6;        // 0 = scanner, 1..2 = loaders
    const int lane  = tid & 63;
    const int bbase = blockIdx.x << 2; // 4 batch rows per block

    // ---------------- scanner per-lane config ----------------
    const int c    = lane >> 4;        // chain 0..3
    const int slot = lane & 15;
    const int chl  = slot >> 3;        // 0 = channel 1, 1 = channel 2
    const int role = slot & 7;         // 0..4 active, 5..7 idle

    const float a0   = chl ? w24[12] : w24[0];
    const float W1v  = chl ? w24[13] : w24[1];
    const float W4v  = chl ? w24[16] : w24[4];
    const float W5v  = chl ? w24[17] : w24[5];
    const float W6v  = chl ? w24[18] : w24[6];
    const float W8v  = chl ? w24[20] : w24[8];
    const float W11v = chl ? w24[23] : w24[11];
    const float W2 = w24[2], W3 = w24[3], W9 = w24[9], W10 = w24[10];

    float pb, pcc, pd, v, u, wA, wB, wC, wD;
    float fL = 0.f, fE = 0.f, fITM = 0.f;
    int offs, srcRole;
    if (role == 0) {        // LLBN: I = w2*(zp*w1) + w3*z2(self prev)
        pb=0.20f; pcc=-65.f; pd=6.f;   v=-70.f; u=-14.f;
        wA=W2;  wB=W1v;  wC=0.f; wD=W3;  offs=0; srcRole=0; fL=1.f;
    } else if (role == 1) { // EBN: I = zp*w4 + z2*w5
        pb=0.25f; pcc=-55.f; pd=0.05f; v=-64.f; u=-16.f;
        wA=1.f; wB=W4v;  wC=W5v; wD=0.f; offs=3; srcRole=0; fE=1.f;
    } else if (role == 2) { // IFN: I = z3*w6
        pb=0.25f; pcc=-65.f; pd=6.f;   v=-64.f; u=-16.f;
        wA=1.f; wB=W6v;  wC=0.f; wD=0.f; offs=6; srcRole=1; fITM=1.f;
    } else if (role == 3) { // TN: I = w9*(z3*w8) + w10*z5(self prev)
        pb=0.20f; pcc=-50.f; pd=2.f;   v=-70.f; u=-14.f;
        wA=W9;  wB=W8v;  wC=0.f; wD=W10; offs=6; srcRole=1; fITM=1.f;
    } else if (role == 4) { // MN: I = z5*w11
        pb=0.25f; pcc=-65.f; pd=6.f;   v=-64.f; u=-16.f;
        wA=1.f; wB=W11v; wC=0.f; wD=0.f; offs=9; srcRole=3; fITM=1.f;
    } else {                // idle
        pb=0.25f; pcc=-65.f; pd=6.f;   v=-64.f; u=-16.f;
        wA=0.f; wB=0.f;  wC=0.f; wD=0.f; offs=9; srcRole=0;
    }
    // ring pairs: ch1 roles 0..4 -> p=0..4 (z2,vL)(z3,vE)(z4,vI)(z5,vT)(z6,vM);
    // ch2 M -> p=5 (z62,vM2). Other lanes don't write.
    const bool wr = (chl == 0 && role <= 4) || (chl == 1 && role == 4);
    const int  p  = (chl == 0) ? role : 5;
    const int srcLane = (c << 4) | (chl << 3) | srcRole;
    const int ringoff = c * 14 + 2 * p;

    float z_last = 0.f, in_p1 = 0.f, in_p2 = 0.f;
    float zp1 = 0.f, zp2 = 0.f, zp3 = 0.f;

    const int lw = wid - 1;            // loader index 0/1 (wave 1/2)

#define REDUCE_WRITE(VV, ROW, I_) {                                            \
    float s_ = ((VV).x + (VV).y) + ((VV).z + (VV).w);                          \
    s_ += __shfl_xor(s_, 1);                                                   \
    s_ += __shfl_xor(s_, 2);                                                   \
    s_ += __shfl_xor(s_, 4);                                                   \
    s_ += __shfl_xor(s_, 8);                                                   \
    if ((lane & 15) == 0) sw[(ROW) * 16 + (I_) * 4 + (lane >> 4)] = s_;        \
}

#define LOAD_GROUP(KK) {                                                       \
    float* sw = S_lds + ((KK) & 1) * 64;                                       \
    const int t0l = 16 * (KK);                                                 \
    const int row0 = lw * 2;                                                   \
    const float4* gb0 = (const float4*)(in + ((size_t)(bbase + row0) * T_ + t0l) * 64);     \
    const float4* gb1 = (const float4*)(in + ((size_t)(bbase + row0 + 1) * T_ + t0l) * 64); \
    float4 v00, v01, v02, v03, v10, v11, v12, v13;                             \
    if (t0l + 15 < T_) {                                                       \
        v00 = gb0[lane]; v01 = gb0[64 + lane];                                 \
        v02 = gb0[128 + lane]; v03 = gb0[192 + lane];                          \
        v10 = gb1[lane]; v11 = gb1[64 + lane];                                 \
        v12 = gb1[128 + lane]; v13 = gb1[192 + lane];                          \
    } else {  /* group 31: only steps 496..499 exist */                        \
        float4 zz = make_float4(0.f, 0.f, 0.f, 0.f);                           \
        v00 = gb0[lane]; v01 = zz; v02 = zz; v03 = zz;                         \
        v10 = gb1[lane]; v11 = zz; v12 = zz; v13 = zz;                         \
    }                                                                          \
    REDUCE_WRITE(v00, row0, 0)     REDUCE_WRITE(v01, row0, 1)                  \
    REDUCE_WRITE(v02, row0, 2)     REDUCE_WRITE(v03, row0, 3)                  \
    REDUCE_WRITE(v10, row0 + 1, 0) REDUCE_WRITE(v11, row0 + 1, 1)              \
    REDUCE_WRITE(v12, row0 + 1, 2) REDUCE_WRITE(v13, row0 + 1, 3)              \
}

#define SYS_ITER(SV, VEXPR, I_) {                                              \
    float in0 = in_p2;                                                         \
    in_p2 = in_p1;                                                             \
    in_p1 = __shfl(z_last, srcLane, 64);                                       \
    float zpc = (SV) * a0;                                                     \
    float X = (fL * zpc + fE * zp3) + fITM * in0;                              \
    float Isyn = wA * (X * wB) + wC * in0 + wD * z_last;                       \
    float znew = izh_m(v, u, Isyn, pb, pcc, pd, (VEXPR));                      \
    if (wr) *(float2*)(ringp + (I_) * 56) = make_float2(znew, v);              \
    zp3 = zp2; zp2 = zp1; zp1 = zpc;                                           \
    z_last = znew;                                                             \
}

#define GROUP16(VF)                                                            \
    SYS_ITER(g0.x, VF(0),  0)  SYS_ITER(g0.y, VF(1),  1)                       \
    SYS_ITER(g0.z, VF(2),  2)  SYS_ITER(g0.w, VF(3),  3)                       \
    SYS_ITER(g1.x, VF(4),  4)  SYS_ITER(g1.y, VF(5),  5)                       \
    SYS_ITER(g1.z, VF(6),  6)  SYS_ITER(g1.w, VF(7),  7)                       \
    SYS_ITER(g2.x, VF(8),  8)  SYS_ITER(g2.y, VF(9),  9)                       \
    SYS_ITER(g2.z, VF(10), 10) SYS_ITER(g2.w, VF(11), 11)                      \
    SYS_ITER(g3.x, VF(12), 12) SYS_ITER(g3.y, VF(13), 13)                      \
    SYS_ITER(g3.z, VF(14), 14) SYS_ITER(g3.w, VF(15), 15)

#define VF_PRO(i)  ((i) >= offs)
#define VF_ONE(i)  true
#define VF_EPI(i)  ((i) <= 3 + offs)

// Dump after group K: t in [16K-9, 16K+6], clamped to [0,499]. One lane per
// (chain, t): reads z2@t, z3@t+3, z4/z5@t+6, z6/z62@t+9 from the ring and
// writes all six output streams (16-consecutive-t coalescing per chain).
#define DUMP(K) {                                                              \
    const int td = lane & 15;                                                  \
    const int cc = lane >> 4;                                                  \
    const int t  = 16 * (K) - 9 + td;                                          \
    if (0 <= t && t <= 499) {                                                  \
        const float* rb = ring + cc * 14;                                      \
        float2 a2 = *(const float2*)&rb[((t)     & 31) * 56 + 0];              \
        float2 b2 = *(const float2*)&rb[((t + 3) & 31) * 56 + 2];              \
        float2 c1 = *(const float2*)&rb[((t + 6) & 31) * 56 + 4];              \
        float2 c2 = *(const float2*)&rb[((t + 6) & 31) * 56 + 6];              \
        float2 e1 = *(const float2*)&rb[((t + 9) & 31) * 56 + 8];              \
        float2 e2 = *(const float2*)&rb[((t + 9) & 31) * 56 + 10];             \
        const size_t g = (size_t)(bbase + cc) * T_ + t;                        \
        out[g]          = e1.x;   /* o_spikes  = z6  */                        \
        out[BT + g]     = e1.y;   /* v         = vM  */                        \
        out[2 * BT + g] = e2.x;   /* o_spikes2 = z62 */                        \
        out[3 * BT + g] = e2.y;   /* v2        = vM2 */                        \
        ((float4*)out)[BT + g]     = make_float4(a2.x, b2.x, c1.x, c2.x);      \
        ((float4*)out)[2 * BT + g] = make_float4(a2.y, b2.y, c1.y, c2.y);      \
    }                                                                          \
}

    // ---------------- pipeline driver (uniform barriers) ----------------
    if (wid) { LOAD_GROUP(0) }
    __syncthreads();                       // S_lds buf0 ready

    for (int k = 0; k <= 30; ++k) {
        if (wid == 0) {
            const float4* sp = (const float4*)(S_lds + (k & 1) * 64 + c * 16);
            float4 g0 = sp[0], g1 = sp[1], g2 = sp[2], g3 = sp[3];
            float* ringp = ring + (k & 1) * 896 + ringoff;
            if (k == 0) { GROUP16(VF_PRO) } else { GROUP16(VF_ONE) }
            DUMP(k)
        } else {
            LOAD_GROUP(k + 1)
        }
        __syncthreads();
    }
    if (wid == 0) {   // group 31 (iters 496..511, validity ramp-down)
        const float4* sp = (const float4*)(S_lds + 64 + c * 16);
        float4 g0 = sp[0], g1 = sp[1], g2 = sp[2], g3 = sp[3];
        float* ringp = ring + 896 + ringoff;
        GROUP16(VF_EPI)
        DUMP(31)
    }

#undef REDUCE_WRITE
#undef LOAD_GROUP
#undef SYS_ITER
#undef GROUP16
#undef VF_PRO
#undef VF_ONE
#undef VF_EPI
#undef DUMP
}

extern "C" void kernel_launch(void* const* d_in, const int* in_sizes, int n_in,
                              void* d_out, int out_size, void* d_ws, size_t ws_size,
                              hipStream_t stream) {
    const float* in = (const float*)d_in[0];
    const float* w  = (const float*)d_in[1];
    float* out = (float*)d_out;

    // 512 blocks x 192 threads (1 scanner wave + 2 loader waves),
    // 4 batch rows per block; no workspace needed.
    fused_scan_kernel<<<512, 192, 0, stream>>>(in, w, out);
}

// Round 10
// 73.470 us; speedup vs baseline: 2.2020x; 1.0794x over previous
//
#include <hip/hip_runtime.h>

#define B_ 2048
#define T_ 500
#define BT (B_ * T_)

// ---------------------------------------------------------------------------
// Masked Izhikevich Euler step — association order matches the reference
// exactly (DT=0.25, all a=0.02 -> DT*a = 0.005f). Invalid lanes hold state.
// ---------------------------------------------------------------------------
__device__ __forceinline__ float izh_m(float& v, float& u, float I,
                                       float b, float c, float d, bool valid) {
    float t  = 0.04f * v * v + 5.0f * v + 140.0f - u + I;
    float v_ = v + 0.25f * t;
    float u_ = u + 0.005f * (b * v - u);
    float z  = (v_ >= 30.0f) ? 1.0f : 0.0f;
    float vn = (v_ >= 30.0f) ? c : v_;
    float un = u_ + z * d;
    if (!valid) { z = 0.f; vn = v; un = u; }
    v = vn; u = un;
    return z;
}

// ---------------------------------------------------------------------------
// FUSED producer-consumer kernel, v2. 512 blocks x 128 threads (2 waves):
//   wave 0 = scanner: gap-3 systolic pipeline (L@j, E@j-3, I/T@j-6, M@j-9),
//            4 chains x 16 slots (slots 0-4 ch1 roles, 8-12 ch2 roles).
//   wave 1 = loader: 2-GROUP-DEEP pipelined input read (issue G(k+2) early
//            into ping-pong reg buffers, reduce G(k+1) from last period's
//            regs) -> HBM latency fully off the period critical path.
// Loader reduction tree is association-IDENTICAL to the original rowsum
// (leaf (x+y)+(z+w); level1 done in-register as s_2c + s_2c+1; then
// shfl_xor 1,2,4) but uses 3 DS ops instead of 4 per value and half the
// lanes. 4 waves/CU => ~one wave per SIMD (scanner gets its own SIMD).
// ---------------------------------------------------------------------------
__global__ __launch_bounds__(128) void fused_scan2_kernel(
        const float* __restrict__ in, const float* __restrict__ w24,
        float* __restrict__ out) {
    __shared__ float S_lds[128];       // [2 bufs][4 rows][16 t]
    __shared__ float ring[32 * 56];    // [32 slots][4 chains * 14 floats]

    const int tid   = threadIdx.x;
    const int wid   = tid >> 6;        // 0 = scanner, 1 = loader
    const int lane  = tid & 63;
    const int bbase = blockIdx.x << 2; // 4 batch rows per block

    // ---------------- scanner per-lane config ----------------
    const int c    = lane >> 4;        // chain 0..3
    const int slot = lane & 15;
    const int chl  = slot >> 3;        // 0 = channel 1, 1 = channel 2
    const int role = slot & 7;         // 0..4 active, 5..7 idle

    const float a0   = chl ? w24[12] : w24[0];
    const float W1v  = chl ? w24[13] : w24[1];
    const float W4v  = chl ? w24[16] : w24[4];
    const float W5v  = chl ? w24[17] : w24[5];
    const float W6v  = chl ? w24[18] : w24[6];
    const float W8v  = chl ? w24[20] : w24[8];
    const float W11v = chl ? w24[23] : w24[11];
    const float W2 = w24[2], W3 = w24[3], W9 = w24[9], W10 = w24[10];

    float pb, pcc, pd, v, u, wA, wB, wC, wD;
    float fL = 0.f, fE = 0.f, fITM = 0.f;
    int offs, srcRole;
    if (role == 0) {        // LLBN: I = w2*(zp*w1) + w3*z2(self prev)
        pb=0.20f; pcc=-65.f; pd=6.f;   v=-70.f; u=-14.f;
        wA=W2;  wB=W1v;  wC=0.f; wD=W3;  offs=0; srcRole=0; fL=1.f;
    } else if (role == 1) { // EBN: I = zp*w4 + z2*w5
        pb=0.25f; pcc=-55.f; pd=0.05f; v=-64.f; u=-16.f;
        wA=1.f; wB=W4v;  wC=W5v; wD=0.f; offs=3; srcRole=0; fE=1.f;
    } else if (role == 2) { // IFN: I = z3*w6
        pb=0.25f; pcc=-65.f; pd=6.f;   v=-64.f; u=-16.f;
        wA=1.f; wB=W6v;  wC=0.f; wD=0.f; offs=6; srcRole=1; fITM=1.f;
    } else if (role == 3) { // TN: I = w9*(z3*w8) + w10*z5(self prev)
        pb=0.20f; pcc=-50.f; pd=2.f;   v=-70.f; u=-14.f;
        wA=W9;  wB=W8v;  wC=0.f; wD=W10; offs=6; srcRole=1; fITM=1.f;
    } else if (role == 4) { // MN: I = z5*w11
        pb=0.25f; pcc=-65.f; pd=6.f;   v=-64.f; u=-16.f;
        wA=1.f; wB=W11v; wC=0.f; wD=0.f; offs=9; srcRole=3; fITM=1.f;
    } else {                // idle
        pb=0.25f; pcc=-65.f; pd=6.f;   v=-64.f; u=-16.f;
        wA=0.f; wB=0.f;  wC=0.f; wD=0.f; offs=9; srcRole=0;
    }
    const bool wr = (chl == 0 && role <= 4) || (chl == 1 && role == 4);
    const int  p  = (chl == 0) ? role : 5;
    const int srcLane = (c << 4) | (chl << 3) | srcRole;
    const int ringoff = c * 14 + 2 * p;

    float z_last = 0.f, in_p1 = 0.f, in_p2 = 0.f;
    float zp1 = 0.f, zp2 = 0.f, zp3 = 0.f;

    const float* inb = in + (size_t)bbase * T_ * 64;
    // loader ping-pong register buffers (static indexing via full unroll)
    float4 Ae[8], Ao[8], Be[8], Bo[8];

#define ISSUE(KK, BE, BO) {                                                    \
    const int t0i = 16 * (KK);                                                 \
    _Pragma("unroll")                                                          \
    for (int pp = 0; pp < 8; ++pp) {                                           \
        const int rt = pp * 8 + (lane >> 3);                                   \
        const int row = rt >> 4, tt = rt & 15;                                 \
        const int tcl = (t0i + tt <= 499) ? tt : 0;                            \
        const float* ap = inb + ((size_t)row * T_ + t0i + tcl) * 64            \
                              + (lane & 7) * 8;                                \
        BE[pp] = *(const float4*)ap;                                           \
        BO[pp] = *(const float4*)(ap + 4);                                     \
    }                                                                          \
}

#define REDUCE(KK, BE, BO) {                                                   \
    float* sw = S_lds + ((KK) & 1) * 64;                                       \
    const int t0r = 16 * (KK);                                                 \
    _Pragma("unroll")                                                          \
    for (int pp = 0; pp < 8; ++pp) {                                           \
        float4 e = BE[pp], o = BO[pp];                                         \
        float s = ((e.x + e.y) + (e.z + e.w)) + ((o.x + o.y) + (o.z + o.w));   \
        s += __shfl_xor(s, 1);                                                 \
        s += __shfl_xor(s, 2);                                                 \
        s += __shfl_xor(s, 4);                                                 \
        const int rt = pp * 8 + (lane >> 3);                                   \
        const int row = rt >> 4, tt = rt & 15;                                 \
        if ((lane & 7) == 0) sw[row * 16 + tt] = (t0r + tt <= 499) ? s : 0.f;  \
    }                                                                          \
}

#define SYS_ITER(SV, VEXPR, I_) {                                              \
    float in0 = in_p2;                                                         \
    in_p2 = in_p1;                                                             \
    in_p1 = __shfl(z_last, srcLane, 64);                                       \
    float zpc = (SV) * a0;                                                     \
    float X = (fL * zpc + fE * zp3) + fITM * in0;                              \
    float Isyn = wA * (X * wB) + wC * in0 + wD * z_last;                       \
    float znew = izh_m(v, u, Isyn, pb, pcc, pd, (VEXPR));                      \
    if (wr) *(float2*)(ringp + (I_) * 56) = make_float2(znew, v);              \
    zp3 = zp2; zp2 = zp1; zp1 = zpc;                                           \
    z_last = znew;                                                             \
}

#define GROUP16(VF)                                                            \
    SYS_ITER(g0.x, VF(0),  0)  SYS_ITER(g0.y, VF(1),  1)                       \
    SYS_ITER(g0.z, VF(2),  2)  SYS_ITER(g0.w, VF(3),  3)                       \
    SYS_ITER(g1.x, VF(4),  4)  SYS_ITER(g1.y, VF(5),  5)                       \
    SYS_ITER(g1.z, VF(6),  6)  SYS_ITER(g1.w, VF(7),  7)                       \
    SYS_ITER(g2.x, VF(8),  8)  SYS_ITER(g2.y, VF(9),  9)                       \
    SYS_ITER(g2.z, VF(10), 10) SYS_ITER(g2.w, VF(11), 11)                      \
    SYS_ITER(g3.x, VF(12), 12) SYS_ITER(g3.y, VF(13), 13)                      \
    SYS_ITER(g3.z, VF(14), 14) SYS_ITER(g3.w, VF(15), 15)

#define VF_PRO(i)  ((i) >= offs)
#define VF_ONE(i)  true
#define VF_EPI(i)  ((i) <= 3 + offs)

#define DUMP(K) {                                                              \
    const int td = lane & 15;                                                  \
    const int cc = lane >> 4;                                                  \
    const int t  = 16 * (K) - 9 + td;                                          \
    if (0 <= t && t <= 499) {                                                  \
        const float* rb = ring + cc * 14;                                      \
        float2 a2 = *(const float2*)&rb[((t)     & 31) * 56 + 0];              \
        float2 b2 = *(const float2*)&rb[((t + 3) & 31) * 56 + 2];              \
        float2 c1 = *(const float2*)&rb[((t + 6) & 31) * 56 + 4];              \
        float2 c2 = *(const float2*)&rb[((t + 6) & 31) * 56 + 6];              \
        float2 e1 = *(const float2*)&rb[((t + 9) & 31) * 56 + 8];              \
        float2 e2 = *(const float2*)&rb[((t + 9) & 31) * 56 + 10];             \
        const size_t g = (size_t)(bbase + cc) * T_ + t;                        \
        out[g]          = e1.x;   /* o_spikes  = z6  */                        \
        out[BT + g]     = e1.y;   /* v         = vM  */                        \
        out[2 * BT + g] = e2.x;   /* o_spikes2 = z62 */                        \
        out[3 * BT + g] = e2.y;   /* v2        = vM2 */                        \
        ((float4*)out)[BT + g]     = make_float4(a2.x, b2.x, c1.x, c2.x);      \
        ((float4*)out)[2 * BT + g] = make_float4(a2.y, b2.y, c1.y, c2.y);      \
    }                                                                          \
}

#define SCANP(K, VFSEL) {                                                      \
    const float4* sp = (const float4*)(S_lds + ((K) & 1) * 64 + c * 16);       \
    float4 g0 = sp[0], g1 = sp[1], g2 = sp[2], g3 = sp[3];                     \
    float* ringp = ring + ((K) & 1) * 896 + ringoff;                           \
    GROUP16(VFSEL)                                                             \
    DUMP(K)                                                                    \
}

    // ---------------- prologue ----------------
    if (wid == 1) {
        ISSUE(0, Ae, Ao)
        REDUCE(0, Ae, Ao)      // compiler inserts the vmcnt wait on consume
        ISSUE(1, Be, Bo)
    }
    __syncthreads();           // S_lds buf0 ready

    // ---------------- main: periods 0..31 (unrolled x2 for reg ping-pong) ---
    for (int k = 0; k < 32; k += 2) {
        // period k (even): scanner G(k); loader: issue G(k+2)->A, reduce G(k+1) from B
        if (wid == 0) {
            if (k == 0) { SCANP(k, VF_PRO) } else { SCANP(k, VF_ONE) }
        } else {
            if (k + 2 < 32) { ISSUE(k + 2, Ae, Ao) }
            if (k + 1 < 32) { REDUCE(k + 1, Be, Bo) }
        }
        __syncthreads();
        // period k+1 (odd): scanner G(k+1); loader: issue G(k+3)->B, reduce G(k+2) from A
        if (wid == 0) {
            if (k + 1 == 31) { SCANP(k + 1, VF_EPI) } else { SCANP(k + 1, VF_ONE) }
        } else {
            if (k + 3 < 32) { ISSUE(k + 3, Be, Bo) }
            if (k + 2 < 32) { REDUCE(k + 2, Ae, Ao) }
        }
        __syncthreads();
    }

#undef ISSUE
#undef REDUCE
#undef SYS_ITER
#undef GROUP16
#undef VF_PRO
#undef VF_ONE
#undef VF_EPI
#undef DUMP
#undef SCANP
}

extern "C" void kernel_launch(void* const* d_in, const int* in_sizes, int n_in,
                              void* d_out, int out_size, void* d_ws, size_t ws_size,
                              hipStream_t stream) {
    const float* in = (const float*)d_in[0];
    const float* w  = (const float*)d_in[1];
    float* out = (float*)d_out;

    // 512 blocks x 128 threads (1 scanner wave + 1 loader wave),
    // 4 batch rows per block; no workspace needed.
    fused_scan2_kernel<<<512, 128, 0, stream>>>(in, w, out);
}